// Round 11
// baseline (2080.527 us; speedup 1.0000x reference)
//
#include <hip/hip_runtime.h>
#include <hip/hip_bf16.h>

constexpr int BATCH = 16;
constexpr int NPT   = 4096;   // points per batch
constexpr int NGRP  = 1024;   // sampled groups
constexpr int NSMP  = 32;     // samples per group
constexpr int NPTS  = BATCH * NGRP * NSMP;  // 524288 total grouped points
constexpr int PBLK  = 4096;   // blocks for pass kernels (128 threads each)
constexpr int NG    = BATCH * NGRP;         // 16384 groups

// exact f32 (no fma contraction) squared distance, numpy order ((x+y)+z)
__device__ __forceinline__ float sqd(float dx, float dy, float dz) {
  return __fadd_rn(__fadd_rn(__fmul_rn(dx, dx), __fmul_rn(dy, dy)), __fmul_rn(dz, dz));
}

// one DPP max-combine level on packed u64 (2x update_dpp + u64 cmp/select, VALU pipe)
template <int CTRL, int RM>
__device__ __forceinline__ unsigned long long dpp_lvl(unsigned long long P) {
  const int lo = (int)(unsigned int)P;
  const int hi = (int)(unsigned int)(P >> 32);
  const int tlo = __builtin_amdgcn_update_dpp(lo, lo, CTRL, RM, 0xF, false);
  const int thi = __builtin_amdgcn_update_dpp(hi, hi, CTRL, RM, 0xF, false);
  const unsigned long long T =
      ((unsigned long long)(unsigned int)thi << 32) | (unsigned int)tlo;
  return (T > P) ? T : P;
}

// ---------------- FPS with spatial pruning: one block (256 thr) per batch ----------------
// Points counting-sorted into 4x4x4 grid cells (LDS). Thread owns 16 CONSECUTIVE sorted
// points (tight AABB). Per step: skip the update if 0.999*lb(c,AABB) >= local max dist
// (provably no dist/argmax change; conservative margin >> f32 rounding). u64 candidate
// packs (dist_bits, ~ORIGINAL idx) so global max + first-original-index tie-break is
// exactly the reference argmax, independent of sort order. DPP reduce + 4-slot exchange
// verbatim from the verified R7 kernel.
__global__ __launch_bounds__(256) void fps_kernel(const float* __restrict__ xyz,
                                                  float* __restrict__ out) {
  __shared__ float sx[NPT], sy[NPT], sz[NPT];
  __shared__ unsigned short soi[NPT];          // original index at sorted pos (8 KB)
  __shared__ unsigned int hist[64], off[64];
  __shared__ unsigned int ex[2][5][4];         // [buf][field: Phi,Plo,x,y,z][wave]
  const int b = blockIdx.x;
  const int t = threadIdx.x;
  const float* src = xyz + (size_t)b * NPT * 3;
  // --- histogram over 4x4x4 cells ---
  if (t < 64) hist[t] = 0;
  __syncthreads();
  float mxv[16], myv[16], mzv[16];
  int myc[16];
  #pragma unroll
  for (int j = 0; j < 16; ++j) {
    const int i = j * 256 + t;
    const float x = src[i * 3 + 0], y = src[i * 3 + 1], z = src[i * 3 + 2];
    mxv[j] = x; myv[j] = y; mzv[j] = z;
    const int cxi = min(3, max(0, (int)(x * 4.0f)));
    const int cyi = min(3, max(0, (int)(y * 4.0f)));
    const int czi = min(3, max(0, (int)(z * 4.0f)));
    myc[j] = cxi * 16 + cyi * 4 + czi;
    atomicAdd(&hist[myc[j]], 1u);
  }
  __syncthreads();
  if (t == 0) {
    unsigned int run = 0;
    for (int c = 0; c < 64; ++c) { off[c] = run; run += hist[c]; }
  }
  __syncthreads();
  // --- scatter into sorted LDS arrays ---
  #pragma unroll
  for (int j = 0; j < 16; ++j) {
    const unsigned int pos = atomicAdd(&off[myc[j]], 1u);
    sx[pos] = mxv[j]; sy[pos] = myv[j]; sz[pos] = mzv[j];
    soi[pos] = (unsigned short)(j * 256 + t);
  }
  __syncthreads();
  // --- ownership: 16 consecutive sorted points per thread; tight AABB ---
  float px[16], py[16], pz[16], dist[16];
  int oir[16];
  float alox = 1e30f, ahix = -1e30f, aloy = 1e30f, ahiy = -1e30f, aloz = 1e30f, ahiz = -1e30f;
  #pragma unroll
  for (int j = 0; j < 16; ++j) {
    const int p = t * 16 + j;
    px[j] = sx[p]; py[j] = sy[p]; pz[j] = sz[p];
    oir[j] = (int)soi[p];
    dist[j] = 1e10f;
    alox = fminf(alox, px[j]); ahix = fmaxf(ahix, px[j]);
    aloy = fminf(aloy, py[j]); ahiy = fmaxf(ahiy, py[j]);
    aloz = fminf(aloz, pz[j]); ahiz = fmaxf(ahiz, pz[j]);
  }
  const int w = t >> 6;
  float cx = src[0], cy = src[1], cz = src[2];   // first centroid = original point 0
  float myMax = 1e10f;                            // forces first update
  float bestd = -1.0f; int bpos = 0; int bestO = 0x7fffffff;
  float* outx = out + (size_t)b * NGRP * 3;
  for (int step = 0; step < NGRP; ++step) {
    if (t == 0) {
      outx[step * 3 + 0] = cx;
      outx[step * 3 + 1] = cy;
      outx[step * 3 + 2] = cz;
    }
    // conservative skip test: lb on d(c, any owned point)
    const float ddx = fmaxf(0.0f, fmaxf(alox - cx, cx - ahix));
    const float ddy = fmaxf(0.0f, fmaxf(aloy - cy, cy - ahiy));
    const float ddz = fmaxf(0.0f, fmaxf(aloz - cz, cz - ahiz));
    const float lb = sqd(ddx, ddy, ddz);
    if (0.999f * lb < myMax) {
      // update + rescan (reference tie-break: max dist, then min ORIGINAL idx)
      bestd = -1.0f; bestO = 0x7fffffff; bpos = 0;
      #pragma unroll
      for (int j = 0; j < 16; ++j) {
        float d = sqd(px[j] - cx, py[j] - cy, pz[j] - cz);
        d = fminf(dist[j], d);
        dist[j] = d;
        if (d > bestd || (d == bestd && oir[j] < bestO)) {
          bestd = d; bestO = oir[j]; bpos = t * 16 + j;
        }
      }
      myMax = bestd;
    }
    const unsigned long long myP =
        ((unsigned long long)__float_as_uint(bestd) << 32) |
        (unsigned long long)(unsigned int)~bestO;
    // speculative coord fetch of own candidate (sorted pos; hidden under DPP chain)
    const float mx = sx[bpos], my_ = sy[bpos], mz = sz[bpos];
    unsigned long long P = myP;
    P = dpp_lvl<0xB1, 0xF>(P);   // quad_perm [1,0,3,2]  (xor1)
    P = dpp_lvl<0x4E, 0xF>(P);   // quad_perm [2,3,0,1]  (xor2)
    P = dpp_lvl<0x141, 0xF>(P);  // row_half_mirror      (merge 4-groups)
    P = dpp_lvl<0x140, 0xF>(P);  // row_mirror           (merge 8-groups)
    P = dpp_lvl<0x142, 0xA>(P);  // row_bcast15, rows 1,3
    P = dpp_lvl<0x143, 0xC>(P);  // row_bcast31, rows 2,3  -> lane 63 has wave max
    const unsigned int flo = (unsigned int)__builtin_amdgcn_readlane((int)(unsigned int)P, 63);
    const unsigned int fhi =
        (unsigned int)__builtin_amdgcn_readlane((int)(unsigned int)(P >> 32), 63);
    const unsigned long long PF = ((unsigned long long)fhi << 32) | flo;
    const int pb = step & 1;
    if (myP == PF) {  // exactly one lane per wave (original idx embedded)
      ex[pb][0][w] = fhi;
      ex[pb][1][w] = flo;
      ex[pb][2][w] = __float_as_uint(mx);
      ex[pb][3][w] = __float_as_uint(my_);
      ex[pb][4][w] = __float_as_uint(mz);
    }
    __syncthreads();
    const unsigned int* e = &ex[pb][0][0];
    unsigned long long best = ((unsigned long long)e[0] << 32) | e[4];
    cx = __uint_as_float(e[8]);
    cy = __uint_as_float(e[12]);
    cz = __uint_as_float(e[16]);
    #pragma unroll
    for (int k = 1; k < 4; ++k) {
      const unsigned long long pk_ = ((unsigned long long)e[k] << 32) | e[4 + k];
      if (pk_ > best) {
        best = pk_;
        cx = __uint_as_float(e[8 + k]);
        cy = __uint_as_float(e[12 + k]);
        cz = __uint_as_float(e[16 + k]);
      }
    }
    // next step writes ex[pb^1]; one barrier per step suffices
  }
}

// ---------------- Ball query + fused input moments ----------------
__global__ __launch_bounds__(256) void ballq_kernel(const float* __restrict__ xyz,
                                                    const float* __restrict__ pf,
                                                    const float* __restrict__ out,
                                                    int* __restrict__ idxg,
                                                    float* __restrict__ part) {
  __shared__ float sx[NPT], sy[NPT], sz[NPT];
  __shared__ int   sel[64 * NSMP];   // 8 KB: this block's selected indices
  __shared__ float cent[64][3];
  const int b = blockIdx.x >> 4;
  const int sub = blockIdx.x & 15;
  const float* src = xyz + (size_t)b * NPT * 3;
  for (int i = threadIdx.x; i < NPT; i += 256) {
    sx[i] = src[i * 3 + 0];
    sy[i] = src[i * 3 + 1];
    sz[i] = src[i * 3 + 2];
  }
  __syncthreads();
  const int lane = threadIdx.x & 63;
  const int w = threadIdx.x >> 6;
  const float R2 = __fmul_rn(0.2f, 0.2f);
  for (int gi = 0; gi < 16; ++gi) {
    const int g = w * 16 + gi;             // group within block
    const int s = sub * 64 + g;            // group within batch
    const float* c = out + ((size_t)b * NGRP + s) * 3;
    const float nx = c[0], ny = c[1], nz = c[2];
    if (lane == 0) { cent[g][0] = nx; cent[g][1] = ny; cent[g][2] = nz; }
    int* og = idxg + ((size_t)b * NGRP + s) * NSMP;
    int* sg = sel + g * NSMP;
    int cnt = 0, firstP = -1;
    for (int base = 0; base < NPT; base += 64) {
      const int p = base + lane;
      const float dsq = sqd(nx - sx[p], ny - sy[p], nz - sz[p]);
      const bool inr = (dsq <= R2);
      unsigned long long m = __ballot(inr);
      if (firstP < 0 && m) firstP = base + (int)__builtin_ctzll(m);
      const int rank = (int)__popcll(m & ((1ull << lane) - 1ull));
      if (inr) {
        const int pos = cnt + rank;
        if (pos < NSMP) { og[pos] = p; sg[pos] = p; }
      }
      cnt += (int)__popcll(m);
      if (cnt >= NSMP) break;
    }
    if (cnt < NSMP) {
      for (int pos = cnt + lane; pos < NSMP; pos += 64) { og[pos] = firstP; sg[pos] = firstP; }
    }
  }
  __syncthreads();
  // phase 2: dense moments over the block's 64*32 samples, 8 per thread (one group each)
  float acc[27];
  #pragma unroll
  for (int k = 0; k < 27; ++k) acc[k] = 0.0f;
  const float* pfb = pf + (size_t)b * NPT * 3;
  const int g2 = threadIdx.x >> 2;           // 8 samples all in group threadIdx.x>>2
  const float c0 = cent[g2][0], c1 = cent[g2][1], c2 = cent[g2][2];
  #pragma unroll
  for (int ii = 0; ii < 8; ++ii) {
    const int si = threadIdx.x * 8 + ii;
    const int i = sel[si];
    float in[6];
    in[0] = sx[i] - c0;
    in[1] = sy[i] - c1;
    in[2] = sz[i] - c2;
    in[3] = pfb[i * 3 + 0];
    in[4] = pfb[i * 3 + 1];
    in[5] = pfb[i * 3 + 2];
    #pragma unroll
    for (int k = 0; k < 6; ++k) acc[k] += in[k];
    int k = 6;
    #pragma unroll
    for (int a = 0; a < 6; ++a)
      #pragma unroll
      for (int bb = a; bb < 6; ++bb) { acc[k] = fmaf(in[a], in[bb], acc[k]); ++k; }
  }
  #pragma unroll
  for (int off = 1; off < 64; off <<= 1) {
    #pragma unroll
    for (int k = 0; k < 27; ++k) acc[k] += __shfl_xor(acc[k], off);
  }
  if (lane == 0) {
    const int slot = blockIdx.x * 4 + w;  // 1024 slots
    #pragma unroll
    for (int k = 0; k < 27; ++k) part[k * 1024 + slot] = acc[k];
  }
}

// ---------------- w3 transpose (for contiguous scalar loads in layer3) ----------------
__global__ void transpose_w3(const float* __restrict__ w3, float* __restrict__ w3t) {
  const int i = blockIdx.x * 256 + threadIdx.x;
  if (i < 128 * 64) {
    const int o = i >> 6, c = i & 63;
    w3t[c * 128 + o] = w3[i];
  }
}

// ---------------- pass helpers ----------------
__device__ __forceinline__ void gather6(const float* __restrict__ xyz, const float* __restrict__ pf,
                                        const float* __restrict__ nxyz, const int* __restrict__ idxg,
                                        int tid, float in[6]) {
  const int g = tid >> 5;
  const int b = g >> 10;
  const int i = idxg[tid];
  const float* P = xyz + ((size_t)b * NPT + i) * 3;
  const float* C = nxyz + (size_t)g * 3;
  in[0] = P[0] - C[0];
  in[1] = P[1] - C[1];
  in[2] = P[2] - C[2];
  const float* F = pf + ((size_t)b * NPT + i) * 3;
  in[3] = F[0]; in[4] = F[1]; in[5] = F[2];
}

__device__ __forceinline__ void layer1h(const float in[6], const float* __restrict__ w1,
                                        const float* __restrict__ b1, const float* __restrict__ ss1,
                                        float h1[64]) {
  #pragma unroll
  for (int o = 0; o < 64; ++o) {
    float a = b1[o];
    #pragma unroll
    for (int cc = 0; cc < 6; ++cc) a = fmaf(in[cc], w1[o * 6 + cc], a);
    h1[o] = fmaxf(0.0f, fmaf(a, ss1[o], ss1[64 + o]));
  }
}

// transpose-reduce over zb[64][129]: thread t sums half-row (c = t>>1, h = t&1)
__device__ __forceinline__ void zb_stats64(const float* zb, float* __restrict__ part,
                                           int chbase, int nch, int t, int blk) {
  const int c = t >> 1, h = t & 1;
  const float* row = zb + c * 129 + h * 64;
  float s = 0.0f, q = 0.0f;
  for (int i = 0; i < 64; ++i) {
    const float v = row[i];
    s += v;
    q = fmaf(v, v, q);
  }
  s += __shfl_xor(s, 1);
  q += __shfl_xor(q, 1);
  if (h == 0) {
    part[(size_t)(chbase + c) * PBLK + blk]       = s;
    part[(size_t)(nch + chbase + c) * PBLK + blk] = q;
  }
}

// stats + per-group (32-point) max/min of z3; groups 2h and 2h+1 within this thread's row
__device__ __forceinline__ void zb_stats_mm(const float* zb, float* __restrict__ part,
                                            float* __restrict__ pmax, float* __restrict__ pmin,
                                            int chbase, int nch, int t, int blk) {
  const int c = t >> 1, h = t & 1;
  const float* row = zb + c * 129 + h * 64;
  float s = 0.0f, q = 0.0f;
  float mx0 = -3.4e38f, mn0 = 3.4e38f, mx1 = -3.4e38f, mn1 = 3.4e38f;
  for (int i = 0; i < 32; ++i) {
    const float v = row[i];
    s += v; q = fmaf(v, v, q);
    mx0 = fmaxf(mx0, v); mn0 = fminf(mn0, v);
  }
  for (int i = 32; i < 64; ++i) {
    const float v = row[i];
    s += v; q = fmaf(v, v, q);
    mx1 = fmaxf(mx1, v); mn1 = fminf(mn1, v);
  }
  s += __shfl_xor(s, 1);
  q += __shfl_xor(q, 1);
  if (h == 0) {
    part[(size_t)(chbase + c) * PBLK + blk]       = s;
    part[(size_t)(nch + chbase + c) * PBLK + blk] = q;
  }
  const size_t g0 = (size_t)blk * 4 + 2 * h;
  pmax[g0 * 128 + chbase + c]       = mx0;
  pmax[(g0 + 1) * 128 + chbase + c] = mx1;
  pmin[g0 * 128 + chbase + c]       = mn0;
  pmin[(g0 + 1) * 128 + chbase + c] = mn1;
}

// parallel f64 reduce of the 27 moment rows (27 blocks x 256 thr)
__global__ __launch_bounds__(256) void momred_kernel(const float* __restrict__ part,
                                                     double* __restrict__ dsum, int n) {
  const int c = blockIdx.x;
  const int t = threadIdx.x;
  double s = 0.0;
  for (int i = t; i < n; i += 256) s += (double)part[c * n + i];
  #pragma unroll
  for (int off = 1; off < 64; off <<= 1) s += __shfl_xor(s, off);
  __shared__ double ls[4];
  const int lane = t & 63, w = t >> 6;
  if (lane == 0) ls[w] = s;
  __syncthreads();
  if (t == 0) dsum[c] = ls[0] + ls[1] + ls[2] + ls[3];
}

// BN1 stats from moments: E[z]=w·E[x]+b ; E[z^2]=w^T M w + 2b(w·E[x]) + b^2 (all f64)
__global__ __launch_bounds__(64) void finalize1_kernel(const double* __restrict__ dsum,
                                                       const float* __restrict__ w1,
                                                       const float* __restrict__ b1,
                                                       const float* __restrict__ g,
                                                       const float* __restrict__ be,
                                                       float* __restrict__ ss) {
  __shared__ double sm[27];
  const int t = threadIdx.x;
  if (t < 27) sm[t] = dsum[t];
  __syncthreads();
  const double N = (double)NPTS;
  double wv[6];
  #pragma unroll
  for (int i = 0; i < 6; ++i) wv[i] = (double)w1[t * 6 + i];
  double mean_wx = 0.0;
  #pragma unroll
  for (int i = 0; i < 6; ++i) mean_wx += wv[i] * sm[i];
  mean_wx /= N;
  const double bb = (double)b1[t];
  const double mu = mean_wx + bb;
  double qq = 0.0;
  int k = 6;
  #pragma unroll
  for (int i = 0; i < 6; ++i)
    #pragma unroll
    for (int j = i; j < 6; ++j) {
      qq += (i == j ? 1.0 : 2.0) * wv[i] * wv[j] * (sm[k] / N);
      ++k;
    }
  const double Ez2 = qq + 2.0 * bb * mean_wx + bb * bb;
  const double var = Ez2 - mu * mu;
  const double inv = 1.0 / sqrt(var + 1e-5);
  ss[t]      = (float)((double)g[t] * inv);
  ss[64 + t] = (float)((double)be[t] - (double)g[t] * mu * inv);
}

// ---------------- stats finalize: one block per channel, deterministic f64 tree ----------------
__global__ __launch_bounds__(256) void reduce_kernel(const float* __restrict__ part, int nblk, int nch,
                                                     const float* __restrict__ g, const float* __restrict__ be,
                                                     float* __restrict__ ss) {
  const int c = blockIdx.x;
  const int t = threadIdx.x;
  double s = 0.0, q = 0.0;
  for (int i = t; i < nblk; i += 256) {
    s += (double)part[(size_t)c * nblk + i];
    q += (double)part[(size_t)(nch + c) * nblk + i];
  }
  #pragma unroll
  for (int off = 1; off < 64; off <<= 1) {
    s += __shfl_xor(s, off);
    q += __shfl_xor(q, off);
  }
  __shared__ double ls[4], lq[4];
  const int lane = t & 63, w = t >> 6;
  if (lane == 0) { ls[w] = s; lq[w] = q; }
  __syncthreads();
  if (t == 0) {
    const double S = ls[0] + ls[1] + ls[2] + ls[3];
    const double Q = lq[0] + lq[1] + lq[2] + lq[3];
    const double n = (double)NPTS;
    const double mu = S / n;
    const double var = Q / n - mu * mu;
    const double inv = 1.0 / sqrt(var + 1e-5);
    ss[c]       = (float)((double)g[c] * inv);
    ss[nch + c] = (float)((double)be[c] - (double)g[c] * mu * inv);
  }
}

// ---------------- pass 2: z2 stats (+ optional bf16 z2 cache) ----------------
__global__ __launch_bounds__(128) void pass2_kernel(const float* __restrict__ xyz, const float* __restrict__ pf,
                                                    const float* __restrict__ nxyz, const int* __restrict__ idxg,
                                                    const float* __restrict__ w1, const float* __restrict__ b1,
                                                    const float* __restrict__ ss1,
                                                    const float* __restrict__ w2, const float* __restrict__ b2,
                                                    float* __restrict__ part,
                                                    __hip_bfloat16* __restrict__ z2c) {
  __shared__ float zb[64 * 129];
  const int t = threadIdx.x;
  const int tid = blockIdx.x * 128 + t;
  float in[6];
  gather6(xyz, pf, nxyz, idxg, tid, in);
  float h1[64];
  layer1h(in, w1, b1, ss1, h1);
  for (int o = 0; o < 64; ++o) {
    float a = b2[o];
    #pragma unroll
    for (int cc = 0; cc < 64; ++cc) a = fmaf(h1[cc], w2[o * 64 + cc], a);
    zb[o * 129 + t] = a;
    if (z2c) z2c[(size_t)o * NPTS + tid] = __float2bfloat16(a);
  }
  __syncthreads();
  zb_stats64(zb, part, 0, 64, t, blockIdx.x);
}

// ---------------- shared body for pass3/pass4: compute acc[128] = z3 ----------------
__device__ __forceinline__ void compute_z3(const float* __restrict__ xyz, const float* __restrict__ pf,
                                           const float* __restrict__ nxyz, const int* __restrict__ idxg,
                                           const float* __restrict__ w1, const float* __restrict__ b1,
                                           const float* __restrict__ ss1,
                                           const float* __restrict__ w2, const float* __restrict__ b2,
                                           const float* __restrict__ ss2,
                                           const float* __restrict__ w3t, const float* __restrict__ b3,
                                           const __hip_bfloat16* __restrict__ z2c,
                                           float* shm, int t, int tid, float acc[128]) {
  float* hrow = shm + t * 65;
  if (z2c) {
    #pragma unroll
    for (int o = 0; o < 64; ++o) {
      const float z = __bfloat162float(z2c[(size_t)o * NPTS + tid]);
      hrow[o] = fmaxf(0.0f, fmaf(z, ss2[o], ss2[64 + o]));
    }
  } else {
    float in[6];
    gather6(xyz, pf, nxyz, idxg, tid, in);
    float h1[64];
    layer1h(in, w1, b1, ss1, h1);
    for (int o = 0; o < 64; ++o) {
      float a = b2[o];
      #pragma unroll
      for (int cc = 0; cc < 64; ++cc) a = fmaf(h1[cc], w2[o * 64 + cc], a);
      hrow[o] = fmaxf(0.0f, fmaf(a, ss2[o], ss2[64 + o]));
    }
  }
  #pragma unroll
  for (int o = 0; o < 128; ++o) acc[o] = b3[o];
  for (int cc = 0; cc < 64; ++cc) {
    const float hc = hrow[cc];
    const float* wrow = w3t + cc * 128;
    #pragma unroll
    for (int o = 0; o < 128; ++o) acc[o] = fmaf(hc, wrow[o], acc[o]);
  }
}

// ---------------- pass 3: z3 stats (+ optional per-group max/min) ----------------
__global__ __launch_bounds__(128) void pass3_kernel(const float* __restrict__ xyz, const float* __restrict__ pf,
                                                    const float* __restrict__ nxyz, const int* __restrict__ idxg,
                                                    const float* __restrict__ w1, const float* __restrict__ b1,
                                                    const float* __restrict__ ss1,
                                                    const float* __restrict__ w2, const float* __restrict__ b2,
                                                    const float* __restrict__ ss2,
                                                    const float* __restrict__ w3t, const float* __restrict__ b3,
                                                    const __hip_bfloat16* __restrict__ z2c,
                                                    float* __restrict__ part,
                                                    float* __restrict__ pmax, float* __restrict__ pmin) {
  __shared__ float shm[8320];
  const int t = threadIdx.x;
  const int tid = blockIdx.x * 128 + t;
  float acc[128];
  compute_z3(xyz, pf, nxyz, idxg, w1, b1, ss1, w2, b2, ss2, w3t, b3, z2c, shm, t, tid, acc);
  __syncthreads();  // all shm (hrow) reads done before overwrite with zb
  // phase A: channels 0..63
  #pragma unroll
  for (int o = 0; o < 64; ++o) shm[o * 129 + t] = acc[o];
  __syncthreads();
  if (pmax) zb_stats_mm(shm, part, pmax, pmin, 0, 128, t, blockIdx.x);
  else      zb_stats64(shm, part, 0, 128, t, blockIdx.x);
  __syncthreads();
  // phase B: channels 64..127
  #pragma unroll
  for (int o = 0; o < 64; ++o) shm[o * 129 + t] = acc[64 + o];
  __syncthreads();
  if (pmax) zb_stats_mm(shm, part, pmax, pmin, 64, 128, t, blockIdx.x);
  else      zb_stats64(shm, part, 64, 128, t, blockIdx.x);
}

// ---------------- pass 4 fast: elementwise BN3+relu on per-group max/min ----------------
__global__ __launch_bounds__(256) void pass4f_kernel(const float* __restrict__ pmax,
                                                     const float* __restrict__ pmin,
                                                     const float* __restrict__ ss3,
                                                     float* __restrict__ outF) {
  const int i = blockIdx.x * 256 + threadIdx.x;  // over NG*128
  const int c = i & 127;
  const float a = ss3[c], bb = ss3[128 + c];
  const float z = (a >= 0.0f) ? pmax[i] : pmin[i];
  outF[i] = fmaxf(0.0f, fmaf(z, a, bb));
}

// ---------------- pass 4 fallback: full recompute (used if ws too small) ----------------
__global__ __launch_bounds__(128) void pass4_kernel(const float* __restrict__ xyz, const float* __restrict__ pf,
                                                    const float* __restrict__ nxyz, const int* __restrict__ idxg,
                                                    const float* __restrict__ w1, const float* __restrict__ b1,
                                                    const float* __restrict__ ss1,
                                                    const float* __restrict__ w2, const float* __restrict__ b2,
                                                    const float* __restrict__ ss2,
                                                    const float* __restrict__ w3t, const float* __restrict__ b3,
                                                    const __hip_bfloat16* __restrict__ z2c,
                                                    const float* __restrict__ ss3,
                                                    float* __restrict__ outF) {
  __shared__ float shm[8320];
  const int t = threadIdx.x;
  const int tid = blockIdx.x * 128 + t;
  float acc[128];
  compute_z3(xyz, pf, nxyz, idxg, w1, b1, ss1, w2, b2, ss2, w3t, b3, z2c, shm, t, tid, acc);
  #pragma unroll
  for (int o = 0; o < 128; ++o)
    acc[o] = fmaxf(0.0f, fmaf(acc[o], ss3[o], ss3[128 + o]));
  __syncthreads();  // shm (hrow) reads done
  const int c4 = t & 63, gp = t >> 6;
  #pragma unroll
  for (int o = 0; o < 64; ++o) shm[o * 129 + t] = acc[o];
  __syncthreads();
  #pragma unroll
  for (int gs = 0; gs < 2; ++gs) {
    const int g = gp * 2 + gs;
    const float* row = shm + c4 * 129 + g * 32;
    float m = row[0];
    for (int i = 1; i < 32; ++i) m = fmaxf(m, row[i]);
    outF[((size_t)blockIdx.x * 4 + g) * 128 + c4] = m;
  }
  __syncthreads();
  #pragma unroll
  for (int o = 0; o < 64; ++o) shm[o * 129 + t] = acc[64 + o];
  __syncthreads();
  #pragma unroll
  for (int gs = 0; gs < 2; ++gs) {
    const int g = gp * 2 + gs;
    const float* row = shm + c4 * 129 + g * 32;
    float m = row[0];
    for (int i = 1; i < 32; ++i) m = fmaxf(m, row[i]);
    outF[((size_t)blockIdx.x * 4 + g) * 128 + 64 + c4] = m;
  }
}

extern "C" void kernel_launch(void* const* d_in, const int* in_sizes, int n_in,
                              void* d_out, int out_size, void* d_ws, size_t ws_size,
                              hipStream_t stream) {
  (void)in_sizes; (void)n_in; (void)out_size;
  const float* xyz = (const float*)d_in[0];
  const float* pf  = (const float*)d_in[1];
  const float* w1  = (const float*)d_in[2];
  const float* b1  = (const float*)d_in[3];
  const float* g1  = (const float*)d_in[4];
  const float* be1 = (const float*)d_in[5];
  const float* w2  = (const float*)d_in[6];
  const float* b2  = (const float*)d_in[7];
  const float* g2  = (const float*)d_in[8];
  const float* be2 = (const float*)d_in[9];
  const float* w3  = (const float*)d_in[10];
  const float* b3  = (const float*)d_in[11];
  const float* g3  = (const float*)d_in[12];
  const float* be3 = (const float*)d_in[13];
  float* out = (float*)d_out;

  int*    idxg = (int*)d_ws;
  float*  p1   = (float*)((char*)d_ws + (size_t)NPTS * 4);   // 27*1024 used
  float*  ss1  = p1 + (size_t)PBLK * 128;
  float*  p2   = ss1 + 128;
  float*  ss2  = p2 + (size_t)PBLK * 128;
  float*  p3   = ss2 + 128;
  float*  ss3  = p3 + (size_t)PBLK * 256;
  float*  w3t  = ss3 + 256;
  double* dsum = (double*)(w3t + 8192);      // 27 doubles (pad to 32)
  float*  pmax = (float*)(dsum + 32);
  float*  pmin = pmax + (size_t)NG * 128;
  __hip_bfloat16* z2c = (__hip_bfloat16*)(pmin + (size_t)NG * 128);
  const size_t needed4 = (size_t)((char*)z2c - (char*)d_ws);
  const size_t needed3 = needed4 + (size_t)NPTS * 64 * sizeof(__hip_bfloat16);
  const bool fast4 = (ws_size >= needed4);
  const bool fast3 = (ws_size >= needed3);
  __hip_bfloat16* z2cp = fast3 ? z2c : nullptr;

  transpose_w3<<<32, 256, 0, stream>>>(w3, w3t);
  fps_kernel<<<BATCH, 256, 0, stream>>>(xyz, out);
  ballq_kernel<<<BATCH * 16, 256, 0, stream>>>(xyz, pf, out, idxg, p1);
  momred_kernel<<<27, 256, 0, stream>>>(p1, dsum, 1024);
  finalize1_kernel<<<1, 64, 0, stream>>>(dsum, w1, b1, g1, be1, ss1);
  pass2_kernel<<<PBLK, 128, 0, stream>>>(xyz, pf, out, idxg, w1, b1, ss1, w2, b2, p2, z2cp);
  reduce_kernel<<<64, 256, 0, stream>>>(p2, PBLK, 64, g2, be2, ss2);
  pass3_kernel<<<PBLK, 128, 0, stream>>>(xyz, pf, out, idxg, w1, b1, ss1, w2, b2, ss2, w3t, b3, z2cp,
                                         p3, fast4 ? pmax : nullptr, fast4 ? pmin : nullptr);
  reduce_kernel<<<128, 256, 0, stream>>>(p3, PBLK, 128, g3, be3, ss3);
  float* outF = out + (size_t)BATCH * NGRP * 3;
  if (fast4) {
    pass4f_kernel<<<(NG * 128) / 256, 256, 0, stream>>>(pmax, pmin, ss3, outF);
  } else {
    pass4_kernel<<<PBLK, 128, 0, stream>>>(xyz, pf, out, idxg, w1, b1, ss1, w2, b2, ss2, w3t, b3,
                                           z2cp, ss3, outF);
  }
}

// Round 12
// 1810.470 us; speedup vs baseline: 1.1492x; 1.1492x over previous
//
#include <hip/hip_runtime.h>
#include <hip/hip_bf16.h>

constexpr int BATCH = 16;
constexpr int NPT   = 4096;   // points per batch
constexpr int NGRP  = 1024;   // sampled groups
constexpr int NSMP  = 32;     // samples per group
constexpr int NPTS  = BATCH * NGRP * NSMP;  // 524288 total grouped points
constexpr int PBLK  = 4096;   // blocks for pass kernels (128 threads each)
constexpr int NG    = BATCH * NGRP;         // 16384 groups

// exact f32 (no fma contraction) squared distance, numpy order ((x+y)+z)
__device__ __forceinline__ float sqd(float dx, float dy, float dz) {
  return __fadd_rn(__fadd_rn(__fmul_rn(dx, dx), __fmul_rn(dy, dy)), __fmul_rn(dz, dz));
}

// one DPP max-combine level on packed u64 (2x update_dpp + u64 cmp/select, VALU pipe)
template <int CTRL, int RM>
__device__ __forceinline__ unsigned long long dpp_lvl(unsigned long long P) {
  const int lo = (int)(unsigned int)P;
  const int hi = (int)(unsigned int)(P >> 32);
  const int tlo = __builtin_amdgcn_update_dpp(lo, lo, CTRL, RM, 0xF, false);
  const int thi = __builtin_amdgcn_update_dpp(hi, hi, CTRL, RM, 0xF, false);
  const unsigned long long T =
      ((unsigned long long)(unsigned int)thi << 32) | (unsigned int)tlo;
  return (T > P) ? T : P;
}

// ---------------- FPS with WAVE-coherent spatial pruning: one block (256 thr) per batch ----
// Counting-sort into 4x4x4 cells. Wave w owns sorted quarter [w*1024,(w+1)*1024), thread
// reads STRIDED within it (conflict-free; tight wave AABB = contiguous sorted slab).
// Per step: whole wave skips the update if 0.999*lb(c, waveAABB) >= wavePrevMax, where
// wavePrevMax is the wave's own DPP-reduced max from last step (free via readlane(63)).
// Skip proof: d(c,p) >= lb >= max dist[p] -> no fminf changes, cached local argmax stays
// valid. Selection = max over (dist, ~orig_idx): partition/order independent -> exactly
// the reference argmax. DPP reduce + 4-slot exchange verbatim from the verified kernel.
__global__ __launch_bounds__(256) void fps_kernel(const float* __restrict__ xyz,
                                                  float* __restrict__ out) {
  __shared__ float sx[NPT], sy[NPT], sz[NPT];
  __shared__ unsigned short soi[NPT];          // original index at sorted pos (8 KB)
  __shared__ unsigned int hist[64], off[64];
  __shared__ unsigned int ex[2][5][4];         // [buf][field: Phi,Plo,x,y,z][wave]
  const int b = blockIdx.x;
  const int t = threadIdx.x;
  const float* src = xyz + (size_t)b * NPT * 3;
  // --- histogram over 4x4x4 cells ---
  if (t < 64) hist[t] = 0;
  __syncthreads();
  float mxv[16], myv[16], mzv[16];
  int myc[16];
  #pragma unroll
  for (int j = 0; j < 16; ++j) {
    const int i = j * 256 + t;
    const float x = src[i * 3 + 0], y = src[i * 3 + 1], z = src[i * 3 + 2];
    mxv[j] = x; myv[j] = y; mzv[j] = z;
    const int cxi = min(3, max(0, (int)(x * 4.0f)));
    const int cyi = min(3, max(0, (int)(y * 4.0f)));
    const int czi = min(3, max(0, (int)(z * 4.0f)));
    myc[j] = cxi * 16 + cyi * 4 + czi;
    atomicAdd(&hist[myc[j]], 1u);
  }
  __syncthreads();
  if (t == 0) {
    unsigned int run = 0;
    for (int c = 0; c < 64; ++c) { off[c] = run; run += hist[c]; }
  }
  __syncthreads();
  #pragma unroll
  for (int j = 0; j < 16; ++j) {
    const unsigned int pos = atomicAdd(&off[myc[j]], 1u);
    sx[pos] = mxv[j]; sy[pos] = myv[j]; sz[pos] = mzv[j];
    soi[pos] = (unsigned short)(j * 256 + t);
  }
  __syncthreads();
  // --- ownership: wave's sorted quarter, strided (conflict-free) ---
  const int lane = t & 63;
  const int w = t >> 6;
  const int wbase = w * 1024;
  float px[16], py[16], pz[16], dist[16];
  int oir[16];
  float lox = 1e30f, hix = -1e30f, loy = 1e30f, hiy = -1e30f, loz = 1e30f, hiz = -1e30f;
  #pragma unroll
  for (int j = 0; j < 16; ++j) {
    const int p = wbase + j * 64 + lane;
    px[j] = sx[p]; py[j] = sy[p]; pz[j] = sz[p];
    oir[j] = (int)soi[p];
    dist[j] = 1e10f;
    lox = fminf(lox, px[j]); hix = fmaxf(hix, px[j]);
    loy = fminf(loy, py[j]); hiy = fmaxf(hiy, py[j]);
    loz = fminf(loz, pz[j]); hiz = fmaxf(hiz, pz[j]);
  }
  // wave AABB: butterfly min/max (one-time); result identical in all lanes -> uniform
  #pragma unroll
  for (int o = 1; o < 64; o <<= 1) {
    lox = fminf(lox, __shfl_xor(lox, o)); hix = fmaxf(hix, __shfl_xor(hix, o));
    loy = fminf(loy, __shfl_xor(loy, o)); hiy = fmaxf(hiy, __shfl_xor(hiy, o));
    loz = fminf(loz, __shfl_xor(loz, o)); hiz = fmaxf(hiz, __shfl_xor(hiz, o));
  }
  float cx = src[0], cy = src[1], cz = src[2];   // first centroid = original point 0
  float wavePrevMax = 1e30f;                      // forces first update
  float bestd = -1.0f; int bestO = 0x7fffffff;
  float mx = 0.0f, my_ = 0.0f, mz = 0.0f;
  float* outx = out + (size_t)b * NGRP * 3;
  for (int step = 0; step < NGRP; ++step) {
    if (t == 0) {
      outx[step * 3 + 0] = cx;
      outx[step * 3 + 1] = cy;
      outx[step * 3 + 2] = cz;
    }
    // wave-uniform skip test (all operands uniform within the wave)
    const float ddx = fmaxf(0.0f, fmaxf(lox - cx, cx - hix));
    const float ddy = fmaxf(0.0f, fmaxf(loy - cy, cy - hiy));
    const float ddz = fmaxf(0.0f, fmaxf(loz - cz, cz - hiz));
    const float lb = sqd(ddx, ddy, ddz);
    if (0.999f * lb < wavePrevMax) {
      bestd = -1.0f; bestO = 0x7fffffff;
      int bj = 0;
      #pragma unroll
      for (int j = 0; j < 16; ++j) {
        float d = sqd(px[j] - cx, py[j] - cy, pz[j] - cz);
        d = fminf(dist[j], d);
        dist[j] = d;
        if (d > bestd || (d == bestd && oir[j] < bestO)) { bestd = d; bestO = oir[j]; bj = j; }
      }
      const int bpos = wbase + bj * 64 + lane;   // bank = lane&31: conflict-free
      mx = sx[bpos]; my_ = sy[bpos]; mz = sz[bpos];  // hidden under DPP chain
    }
    const unsigned long long myP =
        ((unsigned long long)__float_as_uint(bestd) << 32) |
        (unsigned long long)(unsigned int)~bestO;
    unsigned long long P = myP;
    P = dpp_lvl<0xB1, 0xF>(P);   // quad_perm [1,0,3,2]  (xor1)
    P = dpp_lvl<0x4E, 0xF>(P);   // quad_perm [2,3,0,1]  (xor2)
    P = dpp_lvl<0x141, 0xF>(P);  // row_half_mirror      (merge 4-groups)
    P = dpp_lvl<0x140, 0xF>(P);  // row_mirror           (merge 8-groups)
    P = dpp_lvl<0x142, 0xA>(P);  // row_bcast15, rows 1,3
    P = dpp_lvl<0x143, 0xC>(P);  // row_bcast31, rows 2,3  -> lane 63 has wave max
    const unsigned int flo = (unsigned int)__builtin_amdgcn_readlane((int)(unsigned int)P, 63);
    const unsigned int fhi =
        (unsigned int)__builtin_amdgcn_readlane((int)(unsigned int)(P >> 32), 63);
    wavePrevMax = __uint_as_float(fhi);  // wave's current max dist (uniform) — free
    const unsigned long long PF = ((unsigned long long)fhi << 32) | flo;
    const int pb = step & 1;
    if (myP == PF) {  // exactly one lane per wave (original idx embedded)
      ex[pb][0][w] = fhi;
      ex[pb][1][w] = flo;
      ex[pb][2][w] = __float_as_uint(mx);
      ex[pb][3][w] = __float_as_uint(my_);
      ex[pb][4][w] = __float_as_uint(mz);
    }
    __syncthreads();
    const unsigned int* e = &ex[pb][0][0];
    unsigned long long best = ((unsigned long long)e[0] << 32) | e[4];
    cx = __uint_as_float(e[8]);
    cy = __uint_as_float(e[12]);
    cz = __uint_as_float(e[16]);
    #pragma unroll
    for (int k = 1; k < 4; ++k) {
      const unsigned long long pk_ = ((unsigned long long)e[k] << 32) | e[4 + k];
      if (pk_ > best) {
        best = pk_;
        cx = __uint_as_float(e[8 + k]);
        cy = __uint_as_float(e[12 + k]);
        cz = __uint_as_float(e[16 + k]);
      }
    }
    // next step writes ex[pb^1]; one barrier per step suffices
  }
}

// ---------------- Ball query + fused input moments ----------------
__global__ __launch_bounds__(256) void ballq_kernel(const float* __restrict__ xyz,
                                                    const float* __restrict__ pf,
                                                    const float* __restrict__ out,
                                                    int* __restrict__ idxg,
                                                    float* __restrict__ part) {
  __shared__ float sx[NPT], sy[NPT], sz[NPT];
  __shared__ int   sel[64 * NSMP];   // 8 KB: this block's selected indices
  __shared__ float cent[64][3];
  const int b = blockIdx.x >> 4;
  const int sub = blockIdx.x & 15;
  const float* src = xyz + (size_t)b * NPT * 3;
  for (int i = threadIdx.x; i < NPT; i += 256) {
    sx[i] = src[i * 3 + 0];
    sy[i] = src[i * 3 + 1];
    sz[i] = src[i * 3 + 2];
  }
  __syncthreads();
  const int lane = threadIdx.x & 63;
  const int w = threadIdx.x >> 6;
  const float R2 = __fmul_rn(0.2f, 0.2f);
  for (int gi = 0; gi < 16; ++gi) {
    const int g = w * 16 + gi;             // group within block
    const int s = sub * 64 + g;            // group within batch
    const float* c = out + ((size_t)b * NGRP + s) * 3;
    const float nx = c[0], ny = c[1], nz = c[2];
    if (lane == 0) { cent[g][0] = nx; cent[g][1] = ny; cent[g][2] = nz; }
    int* og = idxg + ((size_t)b * NGRP + s) * NSMP;
    int* sg = sel + g * NSMP;
    int cnt = 0, firstP = -1;
    for (int base = 0; base < NPT; base += 64) {
      const int p = base + lane;
      const float dsq = sqd(nx - sx[p], ny - sy[p], nz - sz[p]);
      const bool inr = (dsq <= R2);
      unsigned long long m = __ballot(inr);
      if (firstP < 0 && m) firstP = base + (int)__builtin_ctzll(m);
      const int rank = (int)__popcll(m & ((1ull << lane) - 1ull));
      if (inr) {
        const int pos = cnt + rank;
        if (pos < NSMP) { og[pos] = p; sg[pos] = p; }
      }
      cnt += (int)__popcll(m);
      if (cnt >= NSMP) break;
    }
    if (cnt < NSMP) {
      for (int pos = cnt + lane; pos < NSMP; pos += 64) { og[pos] = firstP; sg[pos] = firstP; }
    }
  }
  __syncthreads();
  // phase 2: dense moments over the block's 64*32 samples, 8 per thread (one group each)
  float acc[27];
  #pragma unroll
  for (int k = 0; k < 27; ++k) acc[k] = 0.0f;
  const float* pfb = pf + (size_t)b * NPT * 3;
  const int g2 = threadIdx.x >> 2;           // 8 samples all in group threadIdx.x>>2
  const float c0 = cent[g2][0], c1 = cent[g2][1], c2 = cent[g2][2];
  #pragma unroll
  for (int ii = 0; ii < 8; ++ii) {
    const int si = threadIdx.x * 8 + ii;
    const int i = sel[si];
    float in[6];
    in[0] = sx[i] - c0;
    in[1] = sy[i] - c1;
    in[2] = sz[i] - c2;
    in[3] = pfb[i * 3 + 0];
    in[4] = pfb[i * 3 + 1];
    in[5] = pfb[i * 3 + 2];
    #pragma unroll
    for (int k = 0; k < 6; ++k) acc[k] += in[k];
    int k = 6;
    #pragma unroll
    for (int a = 0; a < 6; ++a)
      #pragma unroll
      for (int bb = a; bb < 6; ++bb) { acc[k] = fmaf(in[a], in[bb], acc[k]); ++k; }
  }
  #pragma unroll
  for (int off = 1; off < 64; off <<= 1) {
    #pragma unroll
    for (int k = 0; k < 27; ++k) acc[k] += __shfl_xor(acc[k], off);
  }
  if (lane == 0) {
    const int slot = blockIdx.x * 4 + w;  // 1024 slots
    #pragma unroll
    for (int k = 0; k < 27; ++k) part[k * 1024 + slot] = acc[k];
  }
}

// ---------------- w3 transpose (for contiguous scalar loads in layer3) ----------------
__global__ void transpose_w3(const float* __restrict__ w3, float* __restrict__ w3t) {
  const int i = blockIdx.x * 256 + threadIdx.x;
  if (i < 128 * 64) {
    const int o = i >> 6, c = i & 63;
    w3t[c * 128 + o] = w3[i];
  }
}

// ---------------- pass helpers ----------------
__device__ __forceinline__ void gather6(const float* __restrict__ xyz, const float* __restrict__ pf,
                                        const float* __restrict__ nxyz, const int* __restrict__ idxg,
                                        int tid, float in[6]) {
  const int g = tid >> 5;
  const int b = g >> 10;
  const int i = idxg[tid];
  const float* P = xyz + ((size_t)b * NPT + i) * 3;
  const float* C = nxyz + (size_t)g * 3;
  in[0] = P[0] - C[0];
  in[1] = P[1] - C[1];
  in[2] = P[2] - C[2];
  const float* F = pf + ((size_t)b * NPT + i) * 3;
  in[3] = F[0]; in[4] = F[1]; in[5] = F[2];
}

__device__ __forceinline__ void layer1h(const float in[6], const float* __restrict__ w1,
                                        const float* __restrict__ b1, const float* __restrict__ ss1,
                                        float h1[64]) {
  #pragma unroll
  for (int o = 0; o < 64; ++o) {
    float a = b1[o];
    #pragma unroll
    for (int cc = 0; cc < 6; ++cc) a = fmaf(in[cc], w1[o * 6 + cc], a);
    h1[o] = fmaxf(0.0f, fmaf(a, ss1[o], ss1[64 + o]));
  }
}

// transpose-reduce over zb[64][129]: thread t sums half-row (c = t>>1, h = t&1)
__device__ __forceinline__ void zb_stats64(const float* zb, float* __restrict__ part,
                                           int chbase, int nch, int t, int blk) {
  const int c = t >> 1, h = t & 1;
  const float* row = zb + c * 129 + h * 64;
  float s = 0.0f, q = 0.0f;
  for (int i = 0; i < 64; ++i) {
    const float v = row[i];
    s += v;
    q = fmaf(v, v, q);
  }
  s += __shfl_xor(s, 1);
  q += __shfl_xor(q, 1);
  if (h == 0) {
    part[(size_t)(chbase + c) * PBLK + blk]       = s;
    part[(size_t)(nch + chbase + c) * PBLK + blk] = q;
  }
}

// stats + per-group (32-point) max/min of z3; groups 2h and 2h+1 within this thread's row
__device__ __forceinline__ void zb_stats_mm(const float* zb, float* __restrict__ part,
                                            float* __restrict__ pmax, float* __restrict__ pmin,
                                            int chbase, int nch, int t, int blk) {
  const int c = t >> 1, h = t & 1;
  const float* row = zb + c * 129 + h * 64;
  float s = 0.0f, q = 0.0f;
  float mx0 = -3.4e38f, mn0 = 3.4e38f, mx1 = -3.4e38f, mn1 = 3.4e38f;
  for (int i = 0; i < 32; ++i) {
    const float v = row[i];
    s += v; q = fmaf(v, v, q);
    mx0 = fmaxf(mx0, v); mn0 = fminf(mn0, v);
  }
  for (int i = 32; i < 64; ++i) {
    const float v = row[i];
    s += v; q = fmaf(v, v, q);
    mx1 = fmaxf(mx1, v); mn1 = fminf(mn1, v);
  }
  s += __shfl_xor(s, 1);
  q += __shfl_xor(q, 1);
  if (h == 0) {
    part[(size_t)(chbase + c) * PBLK + blk]       = s;
    part[(size_t)(nch + chbase + c) * PBLK + blk] = q;
  }
  const size_t g0 = (size_t)blk * 4 + 2 * h;
  pmax[g0 * 128 + chbase + c]       = mx0;
  pmax[(g0 + 1) * 128 + chbase + c] = mx1;
  pmin[g0 * 128 + chbase + c]       = mn0;
  pmin[(g0 + 1) * 128 + chbase + c] = mn1;
}

// parallel f64 reduce of the 27 moment rows (27 blocks x 256 thr)
__global__ __launch_bounds__(256) void momred_kernel(const float* __restrict__ part,
                                                     double* __restrict__ dsum, int n) {
  const int c = blockIdx.x;
  const int t = threadIdx.x;
  double s = 0.0;
  for (int i = t; i < n; i += 256) s += (double)part[c * n + i];
  #pragma unroll
  for (int off = 1; off < 64; off <<= 1) s += __shfl_xor(s, off);
  __shared__ double ls[4];
  const int lane = t & 63, w = t >> 6;
  if (lane == 0) ls[w] = s;
  __syncthreads();
  if (t == 0) dsum[c] = ls[0] + ls[1] + ls[2] + ls[3];
}

// BN1 stats from moments: E[z]=w·E[x]+b ; E[z^2]=w^T M w + 2b(w·E[x]) + b^2 (all f64)
__global__ __launch_bounds__(64) void finalize1_kernel(const double* __restrict__ dsum,
                                                       const float* __restrict__ w1,
                                                       const float* __restrict__ b1,
                                                       const float* __restrict__ g,
                                                       const float* __restrict__ be,
                                                       float* __restrict__ ss) {
  __shared__ double sm[27];
  const int t = threadIdx.x;
  if (t < 27) sm[t] = dsum[t];
  __syncthreads();
  const double N = (double)NPTS;
  double wv[6];
  #pragma unroll
  for (int i = 0; i < 6; ++i) wv[i] = (double)w1[t * 6 + i];
  double mean_wx = 0.0;
  #pragma unroll
  for (int i = 0; i < 6; ++i) mean_wx += wv[i] * sm[i];
  mean_wx /= N;
  const double bb = (double)b1[t];
  const double mu = mean_wx + bb;
  double qq = 0.0;
  int k = 6;
  #pragma unroll
  for (int i = 0; i < 6; ++i)
    #pragma unroll
    for (int j = i; j < 6; ++j) {
      qq += (i == j ? 1.0 : 2.0) * wv[i] * wv[j] * (sm[k] / N);
      ++k;
    }
  const double Ez2 = qq + 2.0 * bb * mean_wx + bb * bb;
  const double var = Ez2 - mu * mu;
  const double inv = 1.0 / sqrt(var + 1e-5);
  ss[t]      = (float)((double)g[t] * inv);
  ss[64 + t] = (float)((double)be[t] - (double)g[t] * mu * inv);
}

// ---------------- stats finalize: one block per channel, deterministic f64 tree ----------------
__global__ __launch_bounds__(256) void reduce_kernel(const float* __restrict__ part, int nblk, int nch,
                                                     const float* __restrict__ g, const float* __restrict__ be,
                                                     float* __restrict__ ss) {
  const int c = blockIdx.x;
  const int t = threadIdx.x;
  double s = 0.0, q = 0.0;
  for (int i = t; i < nblk; i += 256) {
    s += (double)part[(size_t)c * nblk + i];
    q += (double)part[(size_t)(nch + c) * nblk + i];
  }
  #pragma unroll
  for (int off = 1; off < 64; off <<= 1) {
    s += __shfl_xor(s, off);
    q += __shfl_xor(q, off);
  }
  __shared__ double ls[4], lq[4];
  const int lane = t & 63, w = t >> 6;
  if (lane == 0) { ls[w] = s; lq[w] = q; }
  __syncthreads();
  if (t == 0) {
    const double S = ls[0] + ls[1] + ls[2] + ls[3];
    const double Q = lq[0] + lq[1] + lq[2] + lq[3];
    const double n = (double)NPTS;
    const double mu = S / n;
    const double var = Q / n - mu * mu;
    const double inv = 1.0 / sqrt(var + 1e-5);
    ss[c]       = (float)((double)g[c] * inv);
    ss[nch + c] = (float)((double)be[c] - (double)g[c] * mu * inv);
  }
}

// ---------------- pass 2: z2 stats (+ optional bf16 z2 cache) ----------------
__global__ __launch_bounds__(128) void pass2_kernel(const float* __restrict__ xyz, const float* __restrict__ pf,
                                                    const float* __restrict__ nxyz, const int* __restrict__ idxg,
                                                    const float* __restrict__ w1, const float* __restrict__ b1,
                                                    const float* __restrict__ ss1,
                                                    const float* __restrict__ w2, const float* __restrict__ b2,
                                                    float* __restrict__ part,
                                                    __hip_bfloat16* __restrict__ z2c) {
  __shared__ float zb[64 * 129];
  const int t = threadIdx.x;
  const int tid = blockIdx.x * 128 + t;
  float in[6];
  gather6(xyz, pf, nxyz, idxg, tid, in);
  float h1[64];
  layer1h(in, w1, b1, ss1, h1);
  for (int o = 0; o < 64; ++o) {
    float a = b2[o];
    #pragma unroll
    for (int cc = 0; cc < 64; ++cc) a = fmaf(h1[cc], w2[o * 64 + cc], a);
    zb[o * 129 + t] = a;
    if (z2c) z2c[(size_t)o * NPTS + tid] = __float2bfloat16(a);
  }
  __syncthreads();
  zb_stats64(zb, part, 0, 64, t, blockIdx.x);
}

// ---------------- shared body for pass3/pass4: compute acc[128] = z3 ----------------
__device__ __forceinline__ void compute_z3(const float* __restrict__ xyz, const float* __restrict__ pf,
                                           const float* __restrict__ nxyz, const int* __restrict__ idxg,
                                           const float* __restrict__ w1, const float* __restrict__ b1,
                                           const float* __restrict__ ss1,
                                           const float* __restrict__ w2, const float* __restrict__ b2,
                                           const float* __restrict__ ss2,
                                           const float* __restrict__ w3t, const float* __restrict__ b3,
                                           const __hip_bfloat16* __restrict__ z2c,
                                           float* shm, int t, int tid, float acc[128]) {
  float* hrow = shm + t * 65;
  if (z2c) {
    #pragma unroll
    for (int o = 0; o < 64; ++o) {
      const float z = __bfloat162float(z2c[(size_t)o * NPTS + tid]);
      hrow[o] = fmaxf(0.0f, fmaf(z, ss2[o], ss2[64 + o]));
    }
  } else {
    float in[6];
    gather6(xyz, pf, nxyz, idxg, tid, in);
    float h1[64];
    layer1h(in, w1, b1, ss1, h1);
    for (int o = 0; o < 64; ++o) {
      float a = b2[o];
      #pragma unroll
      for (int cc = 0; cc < 64; ++cc) a = fmaf(h1[cc], w2[o * 64 + cc], a);
      hrow[o] = fmaxf(0.0f, fmaf(a, ss2[o], ss2[64 + o]));
    }
  }
  #pragma unroll
  for (int o = 0; o < 128; ++o) acc[o] = b3[o];
  for (int cc = 0; cc < 64; ++cc) {
    const float hc = hrow[cc];
    const float* wrow = w3t + cc * 128;
    #pragma unroll
    for (int o = 0; o < 128; ++o) acc[o] = fmaf(hc, wrow[o], acc[o]);
  }
}

// ---------------- pass 3: z3 stats (+ optional per-group max/min) ----------------
__global__ __launch_bounds__(128) void pass3_kernel(const float* __restrict__ xyz, const float* __restrict__ pf,
                                                    const float* __restrict__ nxyz, const int* __restrict__ idxg,
                                                    const float* __restrict__ w1, const float* __restrict__ b1,
                                                    const float* __restrict__ ss1,
                                                    const float* __restrict__ w2, const float* __restrict__ b2,
                                                    const float* __restrict__ ss2,
                                                    const float* __restrict__ w3t, const float* __restrict__ b3,
                                                    const __hip_bfloat16* __restrict__ z2c,
                                                    float* __restrict__ part,
                                                    float* __restrict__ pmax, float* __restrict__ pmin) {
  __shared__ float shm[8320];
  const int t = threadIdx.x;
  const int tid = blockIdx.x * 128 + t;
  float acc[128];
  compute_z3(xyz, pf, nxyz, idxg, w1, b1, ss1, w2, b2, ss2, w3t, b3, z2c, shm, t, tid, acc);
  __syncthreads();  // all shm (hrow) reads done before overwrite with zb
  // phase A: channels 0..63
  #pragma unroll
  for (int o = 0; o < 64; ++o) shm[o * 129 + t] = acc[o];
  __syncthreads();
  if (pmax) zb_stats_mm(shm, part, pmax, pmin, 0, 128, t, blockIdx.x);
  else      zb_stats64(shm, part, 0, 128, t, blockIdx.x);
  __syncthreads();
  // phase B: channels 64..127
  #pragma unroll
  for (int o = 0; o < 64; ++o) shm[o * 129 + t] = acc[64 + o];
  __syncthreads();
  if (pmax) zb_stats_mm(shm, part, pmax, pmin, 64, 128, t, blockIdx.x);
  else      zb_stats64(shm, part, 64, 128, t, blockIdx.x);
}

// ---------------- pass 4 fast: elementwise BN3+relu on per-group max/min ----------------
__global__ __launch_bounds__(256) void pass4f_kernel(const float* __restrict__ pmax,
                                                     const float* __restrict__ pmin,
                                                     const float* __restrict__ ss3,
                                                     float* __restrict__ outF) {
  const int i = blockIdx.x * 256 + threadIdx.x;  // over NG*128
  const int c = i & 127;
  const float a = ss3[c], bb = ss3[128 + c];
  const float z = (a >= 0.0f) ? pmax[i] : pmin[i];
  outF[i] = fmaxf(0.0f, fmaf(z, a, bb));
}

// ---------------- pass 4 fallback: full recompute (used if ws too small) ----------------
__global__ __launch_bounds__(128) void pass4_kernel(const float* __restrict__ xyz, const float* __restrict__ pf,
                                                    const float* __restrict__ nxyz, const int* __restrict__ idxg,
                                                    const float* __restrict__ w1, const float* __restrict__ b1,
                                                    const float* __restrict__ ss1,
                                                    const float* __restrict__ w2, const float* __restrict__ b2,
                                                    const float* __restrict__ ss2,
                                                    const float* __restrict__ w3t, const float* __restrict__ b3,
                                                    const __hip_bfloat16* __restrict__ z2c,
                                                    const float* __restrict__ ss3,
                                                    float* __restrict__ outF) {
  __shared__ float shm[8320];
  const int t = threadIdx.x;
  const int tid = blockIdx.x * 128 + t;
  float acc[128];
  compute_z3(xyz, pf, nxyz, idxg, w1, b1, ss1, w2, b2, ss2, w3t, b3, z2c, shm, t, tid, acc);
  #pragma unroll
  for (int o = 0; o < 128; ++o)
    acc[o] = fmaxf(0.0f, fmaf(acc[o], ss3[o], ss3[128 + o]));
  __syncthreads();  // shm (hrow) reads done
  const int c4 = t & 63, gp = t >> 6;
  #pragma unroll
  for (int o = 0; o < 64; ++o) shm[o * 129 + t] = acc[o];
  __syncthreads();
  #pragma unroll
  for (int gs = 0; gs < 2; ++gs) {
    const int g = gp * 2 + gs;
    const float* row = shm + c4 * 129 + g * 32;
    float m = row[0];
    for (int i = 1; i < 32; ++i) m = fmaxf(m, row[i]);
    outF[((size_t)blockIdx.x * 4 + g) * 128 + c4] = m;
  }
  __syncthreads();
  #pragma unroll
  for (int o = 0; o < 64; ++o) shm[o * 129 + t] = acc[64 + o];
  __syncthreads();
  #pragma unroll
  for (int gs = 0; gs < 2; ++gs) {
    const int g = gp * 2 + gs;
    const float* row = shm + c4 * 129 + g * 32;
    float m = row[0];
    for (int i = 1; i < 32; ++i) m = fmaxf(m, row[i]);
    outF[((size_t)blockIdx.x * 4 + g) * 128 + 64 + c4] = m;
  }
}

extern "C" void kernel_launch(void* const* d_in, const int* in_sizes, int n_in,
                              void* d_out, int out_size, void* d_ws, size_t ws_size,
                              hipStream_t stream) {
  (void)in_sizes; (void)n_in; (void)out_size;
  const float* xyz = (const float*)d_in[0];
  const float* pf  = (const float*)d_in[1];
  const float* w1  = (const float*)d_in[2];
  const float* b1  = (const float*)d_in[3];
  const float* g1  = (const float*)d_in[4];
  const float* be1 = (const float*)d_in[5];
  const float* w2  = (const float*)d_in[6];
  const float* b2  = (const float*)d_in[7];
  const float* g2  = (const float*)d_in[8];
  const float* be2 = (const float*)d_in[9];
  const float* w3  = (const float*)d_in[10];
  const float* b3  = (const float*)d_in[11];
  const float* g3  = (const float*)d_in[12];
  const float* be3 = (const float*)d_in[13];
  float* out = (float*)d_out;

  int*    idxg = (int*)d_ws;
  float*  p1   = (float*)((char*)d_ws + (size_t)NPTS * 4);   // 27*1024 used
  float*  ss1  = p1 + (size_t)PBLK * 128;
  float*  p2   = ss1 + 128;
  float*  ss2  = p2 + (size_t)PBLK * 128;
  float*  p3   = ss2 + 128;
  float*  ss3  = p3 + (size_t)PBLK * 256;
  float*  w3t  = ss3 + 256;
  double* dsum = (double*)(w3t + 8192);      // 27 doubles (pad to 32)
  float*  pmax = (float*)(dsum + 32);
  float*  pmin = pmax + (size_t)NG * 128;
  __hip_bfloat16* z2c = (__hip_bfloat16*)(pmin + (size_t)NG * 128);
  const size_t needed4 = (size_t)((char*)z2c - (char*)d_ws);
  const size_t needed3 = needed4 + (size_t)NPTS * 64 * sizeof(__hip_bfloat16);
  const bool fast4 = (ws_size >= needed4);
  const bool fast3 = (ws_size >= needed3);
  __hip_bfloat16* z2cp = fast3 ? z2c : nullptr;

  transpose_w3<<<32, 256, 0, stream>>>(w3, w3t);
  fps_kernel<<<BATCH, 256, 0, stream>>>(xyz, out);
  ballq_kernel<<<BATCH * 16, 256, 0, stream>>>(xyz, pf, out, idxg, p1);
  momred_kernel<<<27, 256, 0, stream>>>(p1, dsum, 1024);
  finalize1_kernel<<<1, 64, 0, stream>>>(dsum, w1, b1, g1, be1, ss1);
  pass2_kernel<<<PBLK, 128, 0, stream>>>(xyz, pf, out, idxg, w1, b1, ss1, w2, b2, p2, z2cp);
  reduce_kernel<<<64, 256, 0, stream>>>(p2, PBLK, 64, g2, be2, ss2);
  pass3_kernel<<<PBLK, 128, 0, stream>>>(xyz, pf, out, idxg, w1, b1, ss1, w2, b2, ss2, w3t, b3, z2cp,
                                         p3, fast4 ? pmax : nullptr, fast4 ? pmin : nullptr);
  reduce_kernel<<<128, 256, 0, stream>>>(p3, PBLK, 128, g3, be3, ss3);
  float* outF = out + (size_t)BATCH * NGRP * 3;
  if (fast4) {
    pass4f_kernel<<<(NG * 128) / 256, 256, 0, stream>>>(pmax, pmin, ss3, outF);
  } else {
    pass4_kernel<<<PBLK, 128, 0, stream>>>(xyz, pf, out, idxg, w1, b1, ss1, w2, b2, ss2, w3t, b3,
                                           z2cp, ss3, outF);
  }
}

// Round 13
// 1179.782 us; speedup vs baseline: 1.7635x; 1.5346x over previous
//
#include <hip/hip_runtime.h>
#include <hip/hip_bf16.h>

constexpr int BATCH = 16;
constexpr int NPT   = 4096;   // points per batch
constexpr int NGRP  = 1024;   // sampled groups
constexpr int NSMP  = 32;     // samples per group
constexpr int NPTS  = BATCH * NGRP * NSMP;  // 524288 total grouped points
constexpr int PBLK  = 4096;   // blocks for pass kernels (128 threads each)
constexpr int NG    = BATCH * NGRP;         // 16384 groups

typedef __attribute__((ext_vector_type(2))) float f32x2;

// exact f32 (no fma contraction) squared distance, numpy order ((x+y)+z)
__device__ __forceinline__ float sqd(float dx, float dy, float dz) {
  return __fadd_rn(__fadd_rn(__fmul_rn(dx, dx), __fmul_rn(dy, dy)), __fmul_rn(dz, dz));
}

// one DPP max-combine level on packed u64 (2x update_dpp + u64 cmp/select, VALU pipe)
template <int CTRL, int RM>
__device__ __forceinline__ unsigned long long dpp_lvl(unsigned long long P) {
  const int lo = (int)(unsigned int)P;
  const int hi = (int)(unsigned int)(P >> 32);
  const int tlo = __builtin_amdgcn_update_dpp(lo, lo, CTRL, RM, 0xF, false);
  const int thi = __builtin_amdgcn_update_dpp(hi, hi, CTRL, RM, 0xF, false);
  const unsigned long long T =
      ((unsigned long long)(unsigned int)thi << 32) | (unsigned int)tlo;
  return (T > P) ? T : P;
}

// ---------------- FPS: one block (256 thr) per batch, 16 pts/thread in regs ----------------
// W=4 structure (measured optimum of 8 variants). Dist loop on point PAIRS as f32x2
// (v_pk_add_f32/v_pk_mul_f32). Per-half math is IEEE rn in the exact reference order
// (contract off); comparison sequence identical to the verified scalar loop.
__global__ __launch_bounds__(256) void fps_kernel(const float* __restrict__ xyz,
                                                  float* __restrict__ out) {
  __shared__ float sx[NPT], sy[NPT], sz[NPT];
  __shared__ float cq[NGRP * 3];        // centroid queue (12 KB)
  __shared__ unsigned int ex[2][5][4];  // [buf][field: Phi,Plo,x,y,z][wave]
  const int b = blockIdx.x;
  const int t = threadIdx.x;
  const float* src = xyz + (size_t)b * NPT * 3;
  for (int i = t; i < NPT; i += 256) {
    sx[i] = src[i * 3 + 0];
    sy[i] = src[i * 3 + 1];
    sz[i] = src[i * 3 + 2];
  }
  __syncthreads();
  f32x2 px[8], py[8], pz[8], dist[8];
  #pragma unroll
  for (int m = 0; m < 8; ++m) {
    const int p0 = (2 * m) * 256 + t;
    const int p1 = (2 * m + 1) * 256 + t;
    px[m] = f32x2{sx[p0], sx[p1]};
    py[m] = f32x2{sy[p0], sy[p1]};
    pz[m] = f32x2{sz[p0], sz[p1]};
    dist[m] = f32x2{1e10f, 1e10f};
  }
  const int w = t >> 6;
  float cx = sx[0], cy = sy[0], cz = sz[0];
  for (int step = 0; step < NGRP; ++step) {
    if (t == 0) {
      cq[step * 3 + 0] = cx;
      cq[step * 3 + 1] = cy;
      cq[step * 3 + 2] = cz;
    }
    float bestd = -1.0f; int bi = 0x7fffffff;
    const f32x2 c2x = {cx, cx}, c2y = {cy, cy}, c2z = {cz, cz};
    #pragma unroll
    for (int m = 0; m < 8; ++m) {
      f32x2 d2;
      {
        #pragma clang fp contract(off)
        const f32x2 dx = px[m] - c2x;
        const f32x2 dy = py[m] - c2y;
        const f32x2 dz = pz[m] - c2z;
        d2 = (dx * dx + dy * dy) + dz * dz;   // per-half rn, numpy order
      }
      const float d0 = fminf(dist[m].x, d2.x);
      const float d1 = fminf(dist[m].y, d2.y);
      dist[m].x = d0;
      dist[m].y = d1;
      if (d0 > bestd) { bestd = d0; bi = (2 * m) * 256 + t; }      // ascending j order
      if (d1 > bestd) { bestd = d1; bi = (2 * m + 1) * 256 + t; }  // first-occurrence ties
    }
    const int myidx = bi;
    const unsigned long long myP =
        ((unsigned long long)__float_as_uint(bestd) << 32) |
        (unsigned long long)(unsigned int)~myidx;
    // speculative coord fetch of own candidate (latency hidden under DPP chain)
    const float mx = sx[myidx], my_ = sy[myidx], mz = sz[myidx];
    unsigned long long P = myP;
    P = dpp_lvl<0xB1, 0xF>(P);   // quad_perm [1,0,3,2]  (xor1)
    P = dpp_lvl<0x4E, 0xF>(P);   // quad_perm [2,3,0,1]  (xor2)
    P = dpp_lvl<0x141, 0xF>(P);  // row_half_mirror      (merge 4-groups)
    P = dpp_lvl<0x140, 0xF>(P);  // row_mirror           (merge 8-groups)
    P = dpp_lvl<0x142, 0xA>(P);  // row_bcast15, rows 1,3
    P = dpp_lvl<0x143, 0xC>(P);  // row_bcast31, rows 2,3  -> lane 63 has wave max
    const unsigned int flo = (unsigned int)__builtin_amdgcn_readlane((int)(unsigned int)P, 63);
    const unsigned int fhi =
        (unsigned int)__builtin_amdgcn_readlane((int)(unsigned int)(P >> 32), 63);
    const unsigned long long PF = ((unsigned long long)fhi << 32) | flo;
    const int pb = step & 1;
    if (myP == PF) {  // exactly one lane per wave (idx embedded)
      ex[pb][0][w] = fhi;
      ex[pb][1][w] = flo;
      ex[pb][2][w] = __float_as_uint(mx);
      ex[pb][3][w] = __float_as_uint(my_);
      ex[pb][4][w] = __float_as_uint(mz);
    }
    __syncthreads();
    const unsigned int* e = &ex[pb][0][0];
    unsigned long long best = ((unsigned long long)e[0] << 32) | e[4];
    cx = __uint_as_float(e[8]);
    cy = __uint_as_float(e[12]);
    cz = __uint_as_float(e[16]);
    #pragma unroll
    for (int k = 1; k < 4; ++k) {
      const unsigned long long pk_ = ((unsigned long long)e[k] << 32) | e[4 + k];
      if (pk_ > best) {
        best = pk_;
        cx = __uint_as_float(e[8 + k]);
        cy = __uint_as_float(e[12 + k]);
        cz = __uint_as_float(e[16 + k]);
      }
    }
    // next step writes ex[pb^1]; one barrier per step suffices
  }
  __syncthreads();
  float* outx = out + (size_t)b * NGRP * 3;
  for (int i = t; i < NGRP * 3; i += 256) outx[i] = cq[i];
}

// ---------------- Ball query + fused input moments ----------------
__global__ __launch_bounds__(256) void ballq_kernel(const float* __restrict__ xyz,
                                                    const float* __restrict__ pf,
                                                    const float* __restrict__ out,
                                                    int* __restrict__ idxg,
                                                    float* __restrict__ part) {
  __shared__ float sx[NPT], sy[NPT], sz[NPT];
  __shared__ int   sel[64 * NSMP];   // 8 KB: this block's selected indices
  __shared__ float cent[64][3];
  const int b = blockIdx.x >> 4;
  const int sub = blockIdx.x & 15;
  const float* src = xyz + (size_t)b * NPT * 3;
  for (int i = threadIdx.x; i < NPT; i += 256) {
    sx[i] = src[i * 3 + 0];
    sy[i] = src[i * 3 + 1];
    sz[i] = src[i * 3 + 2];
  }
  __syncthreads();
  const int lane = threadIdx.x & 63;
  const int w = threadIdx.x >> 6;
  const float R2 = __fmul_rn(0.2f, 0.2f);
  for (int gi = 0; gi < 16; ++gi) {
    const int g = w * 16 + gi;             // group within block
    const int s = sub * 64 + g;            // group within batch
    const float* c = out + ((size_t)b * NGRP + s) * 3;
    const float nx = c[0], ny = c[1], nz = c[2];
    if (lane == 0) { cent[g][0] = nx; cent[g][1] = ny; cent[g][2] = nz; }
    int* og = idxg + ((size_t)b * NGRP + s) * NSMP;
    int* sg = sel + g * NSMP;
    int cnt = 0, firstP = -1;
    for (int base = 0; base < NPT; base += 64) {
      const int p = base + lane;
      const float dsq = sqd(nx - sx[p], ny - sy[p], nz - sz[p]);
      const bool inr = (dsq <= R2);
      unsigned long long m = __ballot(inr);
      if (firstP < 0 && m) firstP = base + (int)__builtin_ctzll(m);
      const int rank = (int)__popcll(m & ((1ull << lane) - 1ull));
      if (inr) {
        const int pos = cnt + rank;
        if (pos < NSMP) { og[pos] = p; sg[pos] = p; }
      }
      cnt += (int)__popcll(m);
      if (cnt >= NSMP) break;
    }
    if (cnt < NSMP) {
      for (int pos = cnt + lane; pos < NSMP; pos += 64) { og[pos] = firstP; sg[pos] = firstP; }
    }
  }
  __syncthreads();
  // phase 2: dense moments over the block's 64*32 samples, 8 per thread (one group each)
  float acc[27];
  #pragma unroll
  for (int k = 0; k < 27; ++k) acc[k] = 0.0f;
  const float* pfb = pf + (size_t)b * NPT * 3;
  const int g2 = threadIdx.x >> 2;           // 8 samples all in group threadIdx.x>>2
  const float c0 = cent[g2][0], c1 = cent[g2][1], c2 = cent[g2][2];
  #pragma unroll
  for (int ii = 0; ii < 8; ++ii) {
    const int si = threadIdx.x * 8 + ii;
    const int i = sel[si];
    float in[6];
    in[0] = sx[i] - c0;
    in[1] = sy[i] - c1;
    in[2] = sz[i] - c2;
    in[3] = pfb[i * 3 + 0];
    in[4] = pfb[i * 3 + 1];
    in[5] = pfb[i * 3 + 2];
    #pragma unroll
    for (int k = 0; k < 6; ++k) acc[k] += in[k];
    int k = 6;
    #pragma unroll
    for (int a = 0; a < 6; ++a)
      #pragma unroll
      for (int bb = a; bb < 6; ++bb) { acc[k] = fmaf(in[a], in[bb], acc[k]); ++k; }
  }
  #pragma unroll
  for (int off = 1; off < 64; off <<= 1) {
    #pragma unroll
    for (int k = 0; k < 27; ++k) acc[k] += __shfl_xor(acc[k], off);
  }
  if (lane == 0) {
    const int slot = blockIdx.x * 4 + w;  // 1024 slots
    #pragma unroll
    for (int k = 0; k < 27; ++k) part[k * 1024 + slot] = acc[k];
  }
}

// ---------------- w3 transpose (for contiguous scalar loads in layer3) ----------------
__global__ void transpose_w3(const float* __restrict__ w3, float* __restrict__ w3t) {
  const int i = blockIdx.x * 256 + threadIdx.x;
  if (i < 128 * 64) {
    const int o = i >> 6, c = i & 63;
    w3t[c * 128 + o] = w3[i];
  }
}

// ---------------- pass helpers ----------------
__device__ __forceinline__ void gather6(const float* __restrict__ xyz, const float* __restrict__ pf,
                                        const float* __restrict__ nxyz, const int* __restrict__ idxg,
                                        int tid, float in[6]) {
  const int g = tid >> 5;
  const int b = g >> 10;
  const int i = idxg[tid];
  const float* P = xyz + ((size_t)b * NPT + i) * 3;
  const float* C = nxyz + (size_t)g * 3;
  in[0] = P[0] - C[0];
  in[1] = P[1] - C[1];
  in[2] = P[2] - C[2];
  const float* F = pf + ((size_t)b * NPT + i) * 3;
  in[3] = F[0]; in[4] = F[1]; in[5] = F[2];
}

__device__ __forceinline__ void layer1h(const float in[6], const float* __restrict__ w1,
                                        const float* __restrict__ b1, const float* __restrict__ ss1,
                                        float h1[64]) {
  #pragma unroll
  for (int o = 0; o < 64; ++o) {
    float a = b1[o];
    #pragma unroll
    for (int cc = 0; cc < 6; ++cc) a = fmaf(in[cc], w1[o * 6 + cc], a);
    h1[o] = fmaxf(0.0f, fmaf(a, ss1[o], ss1[64 + o]));
  }
}

// transpose-reduce over zb[64][129]: thread t sums half-row (c = t>>1, h = t&1)
__device__ __forceinline__ void zb_stats64(const float* zb, float* __restrict__ part,
                                           int chbase, int nch, int t, int blk) {
  const int c = t >> 1, h = t & 1;
  const float* row = zb + c * 129 + h * 64;
  float s = 0.0f, q = 0.0f;
  for (int i = 0; i < 64; ++i) {
    const float v = row[i];
    s += v;
    q = fmaf(v, v, q);
  }
  s += __shfl_xor(s, 1);
  q += __shfl_xor(q, 1);
  if (h == 0) {
    part[(size_t)(chbase + c) * PBLK + blk]       = s;
    part[(size_t)(nch + chbase + c) * PBLK + blk] = q;
  }
}

// stats + per-group (32-point) max/min of z3; groups 2h and 2h+1 within this thread's row
__device__ __forceinline__ void zb_stats_mm(const float* zb, float* __restrict__ part,
                                            float* __restrict__ pmax, float* __restrict__ pmin,
                                            int chbase, int nch, int t, int blk) {
  const int c = t >> 1, h = t & 1;
  const float* row = zb + c * 129 + h * 64;
  float s = 0.0f, q = 0.0f;
  float mx0 = -3.4e38f, mn0 = 3.4e38f, mx1 = -3.4e38f, mn1 = 3.4e38f;
  for (int i = 0; i < 32; ++i) {
    const float v = row[i];
    s += v; q = fmaf(v, v, q);
    mx0 = fmaxf(mx0, v); mn0 = fminf(mn0, v);
  }
  for (int i = 32; i < 64; ++i) {
    const float v = row[i];
    s += v; q = fmaf(v, v, q);
    mx1 = fmaxf(mx1, v); mn1 = fminf(mn1, v);
  }
  s += __shfl_xor(s, 1);
  q += __shfl_xor(q, 1);
  if (h == 0) {
    part[(size_t)(chbase + c) * PBLK + blk]       = s;
    part[(size_t)(nch + chbase + c) * PBLK + blk] = q;
  }
  const size_t g0 = (size_t)blk * 4 + 2 * h;
  pmax[g0 * 128 + chbase + c]       = mx0;
  pmax[(g0 + 1) * 128 + chbase + c] = mx1;
  pmin[g0 * 128 + chbase + c]       = mn0;
  pmin[(g0 + 1) * 128 + chbase + c] = mn1;
}

// parallel f64 reduce of the 27 moment rows (27 blocks x 256 thr)
__global__ __launch_bounds__(256) void momred_kernel(const float* __restrict__ part,
                                                     double* __restrict__ dsum, int n) {
  const int c = blockIdx.x;
  const int t = threadIdx.x;
  double s = 0.0;
  for (int i = t; i < n; i += 256) s += (double)part[c * n + i];
  #pragma unroll
  for (int off = 1; off < 64; off <<= 1) s += __shfl_xor(s, off);
  __shared__ double ls[4];
  const int lane = t & 63, w = t >> 6;
  if (lane == 0) ls[w] = s;
  __syncthreads();
  if (t == 0) dsum[c] = ls[0] + ls[1] + ls[2] + ls[3];
}

// BN1 stats from moments: E[z]=w·E[x]+b ; E[z^2]=w^T M w + 2b(w·E[x]) + b^2 (all f64)
__global__ __launch_bounds__(64) void finalize1_kernel(const double* __restrict__ dsum,
                                                       const float* __restrict__ w1,
                                                       const float* __restrict__ b1,
                                                       const float* __restrict__ g,
                                                       const float* __restrict__ be,
                                                       float* __restrict__ ss) {
  __shared__ double sm[27];
  const int t = threadIdx.x;
  if (t < 27) sm[t] = dsum[t];
  __syncthreads();
  const double N = (double)NPTS;
  double wv[6];
  #pragma unroll
  for (int i = 0; i < 6; ++i) wv[i] = (double)w1[t * 6 + i];
  double mean_wx = 0.0;
  #pragma unroll
  for (int i = 0; i < 6; ++i) mean_wx += wv[i] * sm[i];
  mean_wx /= N;
  const double bb = (double)b1[t];
  const double mu = mean_wx + bb;
  double qq = 0.0;
  int k = 6;
  #pragma unroll
  for (int i = 0; i < 6; ++i)
    #pragma unroll
    for (int j = i; j < 6; ++j) {
      qq += (i == j ? 1.0 : 2.0) * wv[i] * wv[j] * (sm[k] / N);
      ++k;
    }
  const double Ez2 = qq + 2.0 * bb * mean_wx + bb * bb;
  const double var = Ez2 - mu * mu;
  const double inv = 1.0 / sqrt(var + 1e-5);
  ss[t]      = (float)((double)g[t] * inv);
  ss[64 + t] = (float)((double)be[t] - (double)g[t] * mu * inv);
}

// ---------------- stats finalize: one block per channel, deterministic f64 tree ----------------
__global__ __launch_bounds__(256) void reduce_kernel(const float* __restrict__ part, int nblk, int nch,
                                                     const float* __restrict__ g, const float* __restrict__ be,
                                                     float* __restrict__ ss) {
  const int c = blockIdx.x;
  const int t = threadIdx.x;
  double s = 0.0, q = 0.0;
  for (int i = t; i < nblk; i += 256) {
    s += (double)part[(size_t)c * nblk + i];
    q += (double)part[(size_t)(nch + c) * nblk + i];
  }
  #pragma unroll
  for (int off = 1; off < 64; off <<= 1) {
    s += __shfl_xor(s, off);
    q += __shfl_xor(q, off);
  }
  __shared__ double ls[4], lq[4];
  const int lane = t & 63, w = t >> 6;
  if (lane == 0) { ls[w] = s; lq[w] = q; }
  __syncthreads();
  if (t == 0) {
    const double S = ls[0] + ls[1] + ls[2] + ls[3];
    const double Q = lq[0] + lq[1] + lq[2] + lq[3];
    const double n = (double)NPTS;
    const double mu = S / n;
    const double var = Q / n - mu * mu;
    const double inv = 1.0 / sqrt(var + 1e-5);
    ss[c]       = (float)((double)g[c] * inv);
    ss[nch + c] = (float)((double)be[c] - (double)g[c] * mu * inv);
  }
}

// ---------------- pass 2: z2 stats (+ optional bf16 z2 cache) ----------------
__global__ __launch_bounds__(128) void pass2_kernel(const float* __restrict__ xyz, const float* __restrict__ pf,
                                                    const float* __restrict__ nxyz, const int* __restrict__ idxg,
                                                    const float* __restrict__ w1, const float* __restrict__ b1,
                                                    const float* __restrict__ ss1,
                                                    const float* __restrict__ w2, const float* __restrict__ b2,
                                                    float* __restrict__ part,
                                                    __hip_bfloat16* __restrict__ z2c) {
  __shared__ float zb[64 * 129];
  const int t = threadIdx.x;
  const int tid = blockIdx.x * 128 + t;
  float in[6];
  gather6(xyz, pf, nxyz, idxg, tid, in);
  float h1[64];
  layer1h(in, w1, b1, ss1, h1);
  for (int o = 0; o < 64; ++o) {
    float a = b2[o];
    #pragma unroll
    for (int cc = 0; cc < 64; ++cc) a = fmaf(h1[cc], w2[o * 64 + cc], a);
    zb[o * 129 + t] = a;
    if (z2c) z2c[(size_t)o * NPTS + tid] = __float2bfloat16(a);
  }
  __syncthreads();
  zb_stats64(zb, part, 0, 64, t, blockIdx.x);
}

// ---------------- shared body for pass3/pass4: compute acc[128] = z3 ----------------
__device__ __forceinline__ void compute_z3(const float* __restrict__ xyz, const float* __restrict__ pf,
                                           const float* __restrict__ nxyz, const int* __restrict__ idxg,
                                           const float* __restrict__ w1, const float* __restrict__ b1,
                                           const float* __restrict__ ss1,
                                           const float* __restrict__ w2, const float* __restrict__ b2,
                                           const float* __restrict__ ss2,
                                           const float* __restrict__ w3t, const float* __restrict__ b3,
                                           const __hip_bfloat16* __restrict__ z2c,
                                           float* shm, int t, int tid, float acc[128]) {
  float* hrow = shm + t * 65;
  if (z2c) {
    #pragma unroll
    for (int o = 0; o < 64; ++o) {
      const float z = __bfloat162float(z2c[(size_t)o * NPTS + tid]);
      hrow[o] = fmaxf(0.0f, fmaf(z, ss2[o], ss2[64 + o]));
    }
  } else {
    float in[6];
    gather6(xyz, pf, nxyz, idxg, tid, in);
    float h1[64];
    layer1h(in, w1, b1, ss1, h1);
    for (int o = 0; o < 64; ++o) {
      float a = b2[o];
      #pragma unroll
      for (int cc = 0; cc < 64; ++cc) a = fmaf(h1[cc], w2[o * 64 + cc], a);
      hrow[o] = fmaxf(0.0f, fmaf(a, ss2[o], ss2[64 + o]));
    }
  }
  #pragma unroll
  for (int o = 0; o < 128; ++o) acc[o] = b3[o];
  for (int cc = 0; cc < 64; ++cc) {
    const float hc = hrow[cc];
    const float* wrow = w3t + cc * 128;
    #pragma unroll
    for (int o = 0; o < 128; ++o) acc[o] = fmaf(hc, wrow[o], acc[o]);
  }
}

// ---------------- pass 3: z3 stats (+ optional per-group max/min) ----------------
__global__ __launch_bounds__(128) void pass3_kernel(const float* __restrict__ xyz, const float* __restrict__ pf,
                                                    const float* __restrict__ nxyz, const int* __restrict__ idxg,
                                                    const float* __restrict__ w1, const float* __restrict__ b1,
                                                    const float* __restrict__ ss1,
                                                    const float* __restrict__ w2, const float* __restrict__ b2,
                                                    const float* __restrict__ ss2,
                                                    const float* __restrict__ w3t, const float* __restrict__ b3,
                                                    const __hip_bfloat16* __restrict__ z2c,
                                                    float* __restrict__ part,
                                                    float* __restrict__ pmax, float* __restrict__ pmin) {
  __shared__ float shm[8320];
  const int t = threadIdx.x;
  const int tid = blockIdx.x * 128 + t;
  float acc[128];
  compute_z3(xyz, pf, nxyz, idxg, w1, b1, ss1, w2, b2, ss2, w3t, b3, z2c, shm, t, tid, acc);
  __syncthreads();  // all shm (hrow) reads done before overwrite with zb
  // phase A: channels 0..63
  #pragma unroll
  for (int o = 0; o < 64; ++o) shm[o * 129 + t] = acc[o];
  __syncthreads();
  if (pmax) zb_stats_mm(shm, part, pmax, pmin, 0, 128, t, blockIdx.x);
  else      zb_stats64(shm, part, 0, 128, t, blockIdx.x);
  __syncthreads();
  // phase B: channels 64..127
  #pragma unroll
  for (int o = 0; o < 64; ++o) shm[o * 129 + t] = acc[64 + o];
  __syncthreads();
  if (pmax) zb_stats_mm(shm, part, pmax, pmin, 64, 128, t, blockIdx.x);
  else      zb_stats64(shm, part, 64, 128, t, blockIdx.x);
}

// ---------------- pass 4 fast: elementwise BN3+relu on per-group max/min ----------------
__global__ __launch_bounds__(256) void pass4f_kernel(const float* __restrict__ pmax,
                                                     const float* __restrict__ pmin,
                                                     const float* __restrict__ ss3,
                                                     float* __restrict__ outF) {
  const int i = blockIdx.x * 256 + threadIdx.x;  // over NG*128
  const int c = i & 127;
  const float a = ss3[c], bb = ss3[128 + c];
  const float z = (a >= 0.0f) ? pmax[i] : pmin[i];
  outF[i] = fmaxf(0.0f, fmaf(z, a, bb));
}

// ---------------- pass 4 fallback: full recompute (used if ws too small) ----------------
__global__ __launch_bounds__(128) void pass4_kernel(const float* __restrict__ xyz, const float* __restrict__ pf,
                                                    const float* __restrict__ nxyz, const int* __restrict__ idxg,
                                                    const float* __restrict__ w1, const float* __restrict__ b1,
                                                    const float* __restrict__ ss1,
                                                    const float* __restrict__ w2, const float* __restrict__ b2,
                                                    const float* __restrict__ ss2,
                                                    const float* __restrict__ w3t, const float* __restrict__ b3,
                                                    const __hip_bfloat16* __restrict__ z2c,
                                                    const float* __restrict__ ss3,
                                                    float* __restrict__ outF) {
  __shared__ float shm[8320];
  const int t = threadIdx.x;
  const int tid = blockIdx.x * 128 + t;
  float acc[128];
  compute_z3(xyz, pf, nxyz, idxg, w1, b1, ss1, w2, b2, ss2, w3t, b3, z2c, shm, t, tid, acc);
  #pragma unroll
  for (int o = 0; o < 128; ++o)
    acc[o] = fmaxf(0.0f, fmaf(acc[o], ss3[o], ss3[128 + o]));
  __syncthreads();  // shm (hrow) reads done
  const int c4 = t & 63, gp = t >> 6;
  #pragma unroll
  for (int o = 0; o < 64; ++o) shm[o * 129 + t] = acc[o];
  __syncthreads();
  #pragma unroll
  for (int gs = 0; gs < 2; ++gs) {
    const int g = gp * 2 + gs;
    const float* row = shm + c4 * 129 + g * 32;
    float m = row[0];
    for (int i = 1; i < 32; ++i) m = fmaxf(m, row[i]);
    outF[((size_t)blockIdx.x * 4 + g) * 128 + c4] = m;
  }
  __syncthreads();
  #pragma unroll
  for (int o = 0; o < 64; ++o) shm[o * 129 + t] = acc[64 + o];
  __syncthreads();
  #pragma unroll
  for (int gs = 0; gs < 2; ++gs) {
    const int g = gp * 2 + gs;
    const float* row = shm + c4 * 129 + g * 32;
    float m = row[0];
    for (int i = 1; i < 32; ++i) m = fmaxf(m, row[i]);
    outF[((size_t)blockIdx.x * 4 + g) * 128 + 64 + c4] = m;
  }
}

extern "C" void kernel_launch(void* const* d_in, const int* in_sizes, int n_in,
                              void* d_out, int out_size, void* d_ws, size_t ws_size,
                              hipStream_t stream) {
  (void)in_sizes; (void)n_in; (void)out_size;
  const float* xyz = (const float*)d_in[0];
  const float* pf  = (const float*)d_in[1];
  const float* w1  = (const float*)d_in[2];
  const float* b1  = (const float*)d_in[3];
  const float* g1  = (const float*)d_in[4];
  const float* be1 = (const float*)d_in[5];
  const float* w2  = (const float*)d_in[6];
  const float* b2  = (const float*)d_in[7];
  const float* g2  = (const float*)d_in[8];
  const float* be2 = (const float*)d_in[9];
  const float* w3  = (const float*)d_in[10];
  const float* b3  = (const float*)d_in[11];
  const float* g3  = (const float*)d_in[12];
  const float* be3 = (const float*)d_in[13];
  float* out = (float*)d_out;

  int*    idxg = (int*)d_ws;
  float*  p1   = (float*)((char*)d_ws + (size_t)NPTS * 4);   // 27*1024 used
  float*  ss1  = p1 + (size_t)PBLK * 128;
  float*  p2   = ss1 + 128;
  float*  ss2  = p2 + (size_t)PBLK * 128;
  float*  p3   = ss2 + 128;
  float*  ss3  = p3 + (size_t)PBLK * 256;
  float*  w3t  = ss3 + 256;
  double* dsum = (double*)(w3t + 8192);      // 27 doubles (pad to 32)
  float*  pmax = (float*)(dsum + 32);
  float*  pmin = pmax + (size_t)NG * 128;
  __hip_bfloat16* z2c = (__hip_bfloat16*)(pmin + (size_t)NG * 128);
  const size_t needed4 = (size_t)((char*)z2c - (char*)d_ws);
  const size_t needed3 = needed4 + (size_t)NPTS * 64 * sizeof(__hip_bfloat16);
  const bool fast4 = (ws_size >= needed4);
  const bool fast3 = (ws_size >= needed3);
  __hip_bfloat16* z2cp = fast3 ? z2c : nullptr;

  transpose_w3<<<32, 256, 0, stream>>>(w3, w3t);
  fps_kernel<<<BATCH, 256, 0, stream>>>(xyz, out);
  ballq_kernel<<<BATCH * 16, 256, 0, stream>>>(xyz, pf, out, idxg, p1);
  momred_kernel<<<27, 256, 0, stream>>>(p1, dsum, 1024);
  finalize1_kernel<<<1, 64, 0, stream>>>(dsum, w1, b1, g1, be1, ss1);
  pass2_kernel<<<PBLK, 128, 0, stream>>>(xyz, pf, out, idxg, w1, b1, ss1, w2, b2, p2, z2cp);
  reduce_kernel<<<64, 256, 0, stream>>>(p2, PBLK, 64, g2, be2, ss2);
  pass3_kernel<<<PBLK, 128, 0, stream>>>(xyz, pf, out, idxg, w1, b1, ss1, w2, b2, ss2, w3t, b3, z2cp,
                                         p3, fast4 ? pmax : nullptr, fast4 ? pmin : nullptr);
  reduce_kernel<<<128, 256, 0, stream>>>(p3, PBLK, 128, g3, be3, ss3);
  float* outF = out + (size_t)BATCH * NGRP * 3;
  if (fast4) {
    pass4f_kernel<<<(NG * 128) / 256, 256, 0, stream>>>(pmax, pmin, ss3, outF);
  } else {
    pass4_kernel<<<PBLK, 128, 0, stream>>>(xyz, pf, out, idxg, w1, b1, ss1, w2, b2, ss2, w3t, b3,
                                           z2cp, ss3, outF);
  }
}